// Round 4
// baseline (15835.620 us; speedup 1.0000x reference)
//
#include <hip/hip_runtime.h>
#include <stdint.h>

#define B_ 8
#define S_ 4096
#define DIN 2048
#define DH 512
#define NG3 1536   // 3 gates * DH
#define NG 16      // workgroups per batch element in the scan
#define ROWS 32    // hidden rows owned per scan workgroup (DH/NG)
#define NWG (NG * B_)

// f64 magnitude-tagged accumulation:
//   each WG adds (partial * 2^20 + 2^40); word complete <=> value >= 15.5*2^40.
// Exact: 2^40 + p*2^20 spans <= 41 binades < 53-bit mantissa; |p|<64 so
// |sum of scaled partials| < 2^30 << 2^39 (no threshold ambiguity).
#define ACC_SCALE    1048576.0              // 2^20
#define ACC_INVSCALE 9.5367431640625e-07    // 2^-20
#define ACC_BIAS     1099511627776.0        // 2^40
#define ACC_FULL     17592186044416.0       // 16 * 2^40
#define ACC_THRESH   17042430230528.0       // 15.5 * 2^40

typedef __attribute__((ext_vector_type(8))) short bf16x8;
typedef __attribute__((ext_vector_type(4))) float f32x4;

__device__ __forceinline__ unsigned short f2bf(float f) {
  unsigned int u = __builtin_bit_cast(unsigned int, f);
  u = u + 0x7FFFu + ((u >> 16) & 1u);   // RNE
  return (unsigned short)(u >> 16);
}
__device__ __forceinline__ float bf2f(unsigned short h) {
  unsigned int u = ((unsigned int)h) << 16;
  return __builtin_bit_cast(float, u);
}
__device__ __forceinline__ float bflo(unsigned u) {
  return __builtin_bit_cast(float, u << 16);
}
__device__ __forceinline__ float bfhi(unsigned u) {
  return __builtin_bit_cast(float, u & 0xFFFF0000u);
}

// ---------------------------------------------------------------------------
// init: zero the 3 rotating accumulator phases (8 batches x 3 x 1024 doubles)
// ---------------------------------------------------------------------------
__global__ void init_state(unsigned long long* ACCu) {
  int id = blockIdx.x * blockDim.x + threadIdx.x;
  if (id < B_ * 3 * 1024) ACCu[id] = 0ULL;
}

// ---------------------------------------------------------------------------
// pack x-side gate weights into Wp[1536][512] bf16 (K-major B operand)
// ---------------------------------------------------------------------------
__global__ void pack_w(const float* __restrict__ Wz, const float* __restrict__ Wr,
                       const float* __restrict__ Wh, unsigned short* __restrict__ Wp) {
  int id = blockIdx.x * blockDim.x + threadIdx.x;
  if (id >= NG3 * DH) return;
  int n = id >> 9, k = id & 511;
  float v;
  if (n < 512)       v = Wz[(size_t)n * 1024 + k];
  else if (n < 1024) v = Wr[(size_t)(n - 512) * 1024 + k];
  else               v = Wh[(size_t)(n - 1024) * 1024 + k];
  Wp[id] = f2bf(v);
}

// ---------------------------------------------------------------------------
// GEMM1: seq[32768][512] (bf16) = X[32768][2048] (f32->bf16) @ Wlm[512][2048]^T
// ---------------------------------------------------------------------------
__global__ __launch_bounds__(256) void gemm1_kernel(
    const float* __restrict__ X, const float* __restrict__ Wlm,
    unsigned short* __restrict__ seqb) {
  __shared__ __align__(16) unsigned short sA[64 * 32];
  __shared__ __align__(16) unsigned short sB[64 * 32];
  const int tid = threadIdx.x;
  const int m0 = blockIdx.x * 64, n0 = blockIdx.y * 64;
  const int lrow = tid >> 2, lpart = tid & 3;
  const int w = tid >> 6, lane = tid & 63;
  const int wm = (w >> 1) * 32, wn = (w & 1) * 32;
  const int l16 = lane & 15, quad = lane >> 4;
  f32x4 acc00 = {0.f, 0.f, 0.f, 0.f}, acc01 = {0.f, 0.f, 0.f, 0.f};
  f32x4 acc10 = {0.f, 0.f, 0.f, 0.f}, acc11 = {0.f, 0.f, 0.f, 0.f};
  const float* ap = X + (size_t)(m0 + lrow) * DIN + lpart * 8;
  const float* bp = Wlm + (size_t)(n0 + lrow) * DIN + lpart * 8;
  for (int k0 = 0; k0 < DIN; k0 += 32) {
    float4 a1 = *(const float4*)(ap + k0);
    float4 a2 = *(const float4*)(ap + k0 + 4);
    float4 b1 = *(const float4*)(bp + k0);
    float4 b2 = *(const float4*)(bp + k0 + 4);
    uint4 pa, pb;
    pa.x = f2bf(a1.x) | ((unsigned)f2bf(a1.y) << 16);
    pa.y = f2bf(a1.z) | ((unsigned)f2bf(a1.w) << 16);
    pa.z = f2bf(a2.x) | ((unsigned)f2bf(a2.y) << 16);
    pa.w = f2bf(a2.z) | ((unsigned)f2bf(a2.w) << 16);
    pb.x = f2bf(b1.x) | ((unsigned)f2bf(b1.y) << 16);
    pb.y = f2bf(b1.z) | ((unsigned)f2bf(b1.w) << 16);
    pb.z = f2bf(b2.x) | ((unsigned)f2bf(b2.y) << 16);
    pb.w = f2bf(b2.z) | ((unsigned)f2bf(b2.w) << 16);
    __syncthreads();
    *(uint4*)(sA + lrow * 32 + lpart * 8) = pa;
    *(uint4*)(sB + lrow * 32 + lpart * 8) = pb;
    __syncthreads();
    uint4 ua0 = *(const uint4*)(sA + (wm + l16) * 32 + quad * 8);
    uint4 ua1 = *(const uint4*)(sA + (wm + 16 + l16) * 32 + quad * 8);
    uint4 ub0 = *(const uint4*)(sB + (wn + l16) * 32 + quad * 8);
    uint4 ub1 = *(const uint4*)(sB + (wn + 16 + l16) * 32 + quad * 8);
    bf16x8 a0 = __builtin_bit_cast(bf16x8, ua0);
    bf16x8 a1f = __builtin_bit_cast(bf16x8, ua1);
    bf16x8 b0 = __builtin_bit_cast(bf16x8, ub0);
    bf16x8 b1f = __builtin_bit_cast(bf16x8, ub1);
    acc00 = __builtin_amdgcn_mfma_f32_16x16x32_bf16(a0, b0, acc00, 0, 0, 0);
    acc01 = __builtin_amdgcn_mfma_f32_16x16x32_bf16(a0, b1f, acc01, 0, 0, 0);
    acc10 = __builtin_amdgcn_mfma_f32_16x16x32_bf16(a1f, b0, acc10, 0, 0, 0);
    acc11 = __builtin_amdgcn_mfma_f32_16x16x32_bf16(a1f, b1f, acc11, 0, 0, 0);
  }
#pragma unroll
  for (int r = 0; r < 4; ++r) {
    int row0 = m0 + wm + quad * 4 + r;
    int row1 = row0 + 16;
    int col0 = n0 + wn + l16;
    seqb[(size_t)row0 * DH + col0] = f2bf(acc00[r]);
    seqb[(size_t)row0 * DH + col0 + 16] = f2bf(acc01[r]);
    seqb[(size_t)row1 * DH + col0] = f2bf(acc10[r]);
    seqb[(size_t)row1 * DH + col0 + 16] = f2bf(acc11[r]);
  }
}

// ---------------------------------------------------------------------------
// GEMM2: G[32768][1536] (bf16) = seq[32768][512] (bf16) @ Wp[1536][512]^T
// ---------------------------------------------------------------------------
__global__ __launch_bounds__(256) void gemm2_kernel(
    const unsigned short* __restrict__ Ab, const unsigned short* __restrict__ Bb,
    unsigned short* __restrict__ Cb) {
  __shared__ __align__(16) unsigned short sA[64 * 32];
  __shared__ __align__(16) unsigned short sB[64 * 32];
  const int tid = threadIdx.x;
  const int m0 = blockIdx.x * 64, n0 = blockIdx.y * 64;
  const int lrow = tid >> 2, lpart = tid & 3;
  const int w = tid >> 6, lane = tid & 63;
  const int wm = (w >> 1) * 32, wn = (w & 1) * 32;
  const int l16 = lane & 15, quad = lane >> 4;
  f32x4 acc00 = {0.f, 0.f, 0.f, 0.f}, acc01 = {0.f, 0.f, 0.f, 0.f};
  f32x4 acc10 = {0.f, 0.f, 0.f, 0.f}, acc11 = {0.f, 0.f, 0.f, 0.f};
  const unsigned short* ap = Ab + (size_t)(m0 + lrow) * DH + lpart * 8;
  const unsigned short* bp = Bb + (size_t)(n0 + lrow) * DH + lpart * 8;
  for (int k0 = 0; k0 < DH; k0 += 32) {
    uint4 pa = *(const uint4*)(ap + k0);
    uint4 pb = *(const uint4*)(bp + k0);
    __syncthreads();
    *(uint4*)(sA + lrow * 32 + lpart * 8) = pa;
    *(uint4*)(sB + lrow * 32 + lpart * 8) = pb;
    __syncthreads();
    uint4 ua0 = *(const uint4*)(sA + (wm + l16) * 32 + quad * 8);
    uint4 ua1 = *(const uint4*)(sA + (wm + 16 + l16) * 32 + quad * 8);
    uint4 ub0 = *(const uint4*)(sB + (wn + l16) * 32 + quad * 8);
    uint4 ub1 = *(const uint4*)(sB + (wn + 16 + l16) * 32 + quad * 8);
    bf16x8 a0 = __builtin_bit_cast(bf16x8, ua0);
    bf16x8 a1f = __builtin_bit_cast(bf16x8, ua1);
    bf16x8 b0 = __builtin_bit_cast(bf16x8, ub0);
    bf16x8 b1f = __builtin_bit_cast(bf16x8, ub1);
    acc00 = __builtin_amdgcn_mfma_f32_16x16x32_bf16(a0, b0, acc00, 0, 0, 0);
    acc01 = __builtin_amdgcn_mfma_f32_16x16x32_bf16(a0, b1f, acc01, 0, 0, 0);
    acc10 = __builtin_amdgcn_mfma_f32_16x16x32_bf16(a1f, b0, acc10, 0, 0, 0);
    acc11 = __builtin_amdgcn_mfma_f32_16x16x32_bf16(a1f, b1f, acc11, 0, 0, 0);
  }
#pragma unroll
  for (int r = 0; r < 4; ++r) {
    int row0 = m0 + wm + quad * 4 + r;
    int row1 = row0 + 16;
    int col0 = n0 + wn + l16;
    Cb[(size_t)row0 * NG3 + col0] = f2bf(acc00[r]);
    Cb[(size_t)row0 * NG3 + col0 + 16] = f2bf(acc01[r]);
    Cb[(size_t)row1 * NG3 + col0] = f2bf(acc10[r]);
    Cb[(size_t)row1 * NG3 + col0 + 16] = f2bf(acc11[r]);
  }
}

// ---------------------------------------------------------------------------
// GRU scan — k-split, ONE exchange hop per step (R3 protocol; R4 de-serialized).
//
// R4 changes (protocol & math identical to R3):
//  * poll: all 4 loads issued per iteration, ONE waitcnt, f64-min compare
//    (R3's per-word if(!d) polls serialized 4 MALL round trips per iteration).
//  * pz publishes deferred past barrier-1, so barrier-1's implicit vmcnt(0)
//    drain only covers the PREVIOUS step's zero-store (issued ~800cy earlier,
//    i.e. free) — and that drain is what orders zero(t) before publish(t+1),
//    keeping the phase-rotation proof intact.
//  * barrier-2 is a raw s_barrier + lgkmcnt(0) (LDS only): the zero-store ACK
//    no longer stalls the loop tail; it is enforced at next barrier-1.
//
// Phase rotation proof (3 phases): adds(t)->phase t%3; zero of phase (t+2)%3
// at step t follows poll(t) (all 16 WGs' adds(t) landed => all passed
// poll(t-1) => all consumed phase (t-1)%3 == (t+2)%3).  adds(t+2) into that
// phase are issued only after poll(t+1), which requires every WG's adds(t+1),
// which are issued after that WG's barrier-1 vmcnt drain => after its zero(t)
// completed at the coherence point.  Bounded spin guards termination.
// ---------------------------------------------------------------------------
__global__ __launch_bounds__(256) void scan_kernel(
    const unsigned short* __restrict__ G, const float* __restrict__ Wz,
    const float* __restrict__ Wr, const float* __restrict__ Wh,
    double* __restrict__ ACC, float* __restrict__ Hout) {
  extern __shared__ char smem[];
  unsigned* sWR = (unsigned*)smem;                  // Wr row-slice  [32][256u] 32KB
  unsigned* sZ  = (unsigned*)(smem + 32768);        // Wz col-slice  [256][32u] 32KB
  unsigned* sH  = (unsigned*)(smem + 65536);        // Wh col-slice  [256][32u] 32KB
  float* hbuf = (float*)(smem + 98304);             // 512 f
  float* vbuf = (float*)(smem + 100352);            // 32 f
  float* grbuf = (float*)(smem + 100480);           // 32 f

  const int tid = threadIdx.x;
  const int wg = blockIdx.x;
  const int b = wg & 7;
  const int slice = wg >> 3;
  const int rbase = slice * ROWS;

  // ---- stage Wr row-slice (h-half cols), 16B-chunk XOR swizzle by row&7 ----
  for (int idx = tid; idx < ROWS * 256; idx += 256) {
    int row = idx >> 8, cu = idx & 255;
    const float* src = Wr + (size_t)(rbase + row) * 1024 + 512 + 2 * cu;
    unsigned u = (unsigned)f2bf(src[0]) | ((unsigned)f2bf(src[1]) << 16);
    int sw = (((cu >> 2) ^ (row & 7)) << 2) | (cu & 3);
    sWR[row * 256 + sw] = u;
  }
  // ---- stage Wz/Wh column-slices: uint (row-pair) x 32 k, chunk-swizzled ----
  for (int idx = tid; idx < 8192; idx += 256) {
    int rp = idx >> 5, k = idx & 31;
    size_t col = 512 + rbase + k;
    unsigned uz = (unsigned)f2bf(Wz[(size_t)(2 * rp) * 1024 + col]) |
                  ((unsigned)f2bf(Wz[(size_t)(2 * rp + 1) * 1024 + col]) << 16);
    unsigned uh = (unsigned)f2bf(Wh[(size_t)(2 * rp) * 1024 + col]) |
                  ((unsigned)f2bf(Wh[(size_t)(2 * rp + 1) * 1024 + col]) << 16);
    int sw = rp * 32 + ((((k >> 2) ^ (rp & 7)) << 2) | (k & 3));
    sZ[sw] = uz;
    sH[sw] = uh;
  }
  // h(0) = 0
  hbuf[2 * tid] = 0.f;
  hbuf[2 * tid + 1] = 0.f;

  const unsigned short* Gb = G + (size_t)b * S_ * NG3;
  double* ACCb = ACC + (size_t)b * 3 * 1024;
  const int tx = tid & 7;
  const int rowB = tid >> 3, part8 = tid & 7, rx = rowB & 7;
  const unsigned* wrow = sWR + rowB * 256;
  const unsigned* zrow = sZ + tid * 32;
  const unsigned* hrow = sH + tid * 32;

  // preload G(0)
  unsigned gzu = *(const unsigned*)(Gb + 2 * tid);
  unsigned ghu = *(const unsigned*)(Gb + 1024 + 2 * tid);
  if (tid < 16) {
    unsigned g = *(const unsigned*)(Gb + 512 + rbase + 2 * tid);
    grbuf[2 * tid] = bflo(g);
    grbuf[2 * tid + 1] = bfhi(g);
  }
  long long spin_budget = 1LL << 22;   // hang guard (never hit when correct)

  __syncthreads();   // weights + hbuf + grbuf staged

  for (int t = 0; t < S_; ++t) {
    double* ACCp = ACCb + (t % 3) * 1024;

    // ---- own-slice h into regs (broadcast LDS reads) ----
    float4 hown[8];
#pragma unroll
    for (int c = 0; c < 8; ++c) hown[c] = *(const float4*)(hbuf + rbase + 4 * c);

    // ---- r exact for own k = rbase+rowB (full h); v local ----
    {
      float s = 0.f;
#pragma unroll
      for (int j = 0; j < 8; ++j) {
        int c = j * 8 + part8;
        uint4 w4 = *(const uint4*)(wrow + ((c ^ rx) << 2));
        const float* hcp = hbuf + (c << 3);
        float4 h0 = *(const float4*)hcp;
        float4 h1 = *(const float4*)(hcp + 4);
        s += bflo(w4.x) * h0.x + bfhi(w4.x) * h0.y;
        s += bflo(w4.y) * h0.z + bfhi(w4.y) * h0.w;
        s += bflo(w4.z) * h1.x + bfhi(w4.z) * h1.y;
        s += bflo(w4.w) * h1.z + bfhi(w4.w) * h1.w;
      }
      s += __shfl_xor(s, 1);
      s += __shfl_xor(s, 2);
      s += __shfl_xor(s, 4);
      if (part8 == 0) {
        float r = 1.f / (1.f + expf(-(grbuf[rowB] + s)));
        vbuf[rowB] = r * hbuf[rbase + rowB];
      }
    }

    // ---- pz partial for rows 2tid, 2tid+1 (compute only; publish deferred) ----
    float pz0 = 0.f, pz1 = 0.f;
#pragma unroll
    for (int c = 0; c < 8; ++c) {
      uint4 w4 = *(const uint4*)(zrow + ((c ^ tx) << 2));
      float4 hk = hown[c];
      pz0 += bflo(w4.x) * hk.x; pz1 += bfhi(w4.x) * hk.x;
      pz0 += bflo(w4.y) * hk.y; pz1 += bfhi(w4.y) * hk.y;
      pz0 += bflo(w4.z) * hk.z; pz1 += bfhi(w4.z) * hk.z;
      pz0 += bflo(w4.w) * hk.w; pz1 += bfhi(w4.w) * hk.w;
    }

    // barrier 1: vbuf ready.  Implicit vmcnt(0) drains the PREVIOUS step's
    // zero-store ACK (issued ~800cy ago -> ~free) — this orders zero(t-1)
    // before publish(t), which the rotation proof requires.
    __syncthreads();

    // ---- publish pz (RMWs fly during ph compute) ----
    unsafeAtomicAdd(ACCp + 2 * tid, (double)pz0 * ACC_SCALE + ACC_BIAS);
    unsafeAtomicAdd(ACCp + 2 * tid + 1, (double)pz1 * ACC_SCALE + ACC_BIAS);

    // ---- ph partial; publish ----
    {
      float4 vown[8];
#pragma unroll
      for (int c = 0; c < 8; ++c) vown[c] = *(const float4*)(vbuf + 4 * c);
      float p0 = 0.f, p1 = 0.f;
#pragma unroll
      for (int c = 0; c < 8; ++c) {
        uint4 w4 = *(const uint4*)(hrow + ((c ^ tx) << 2));
        float4 vk = vown[c];
        p0 += bflo(w4.x) * vk.x; p1 += bfhi(w4.x) * vk.x;
        p0 += bflo(w4.y) * vk.y; p1 += bfhi(w4.y) * vk.y;
        p0 += bflo(w4.z) * vk.z; p1 += bfhi(w4.z) * vk.z;
        p0 += bflo(w4.w) * vk.w; p1 += bfhi(w4.w) * vk.w;
      }
      unsafeAtomicAdd(ACCp + 512 + 2 * tid, (double)p0 * ACC_SCALE + ACC_BIAS);
      unsafeAtomicAdd(ACCp + 512 + 2 * tid + 1, (double)p1 * ACC_SCALE + ACC_BIAS);
    }

    // ---- prefetch G(t+1) (overlaps the poll) ----
    unsigned gzu2 = gzu, ghu2 = ghu, gru2 = 0;
    if (t + 1 < S_) {
      const unsigned short* Gt = Gb + (size_t)(t + 1) * NG3;
      gzu2 = *(const unsigned*)(Gt + 2 * tid);
      ghu2 = *(const unsigned*)(Gt + 1024 + 2 * tid);
      if (tid < 16) gru2 = *(const unsigned*)(Gt + 512 + rbase + 2 * tid);
    }

    // ---- poll own 4 words: 4 loads per iteration, ONE wait, min-compare ----
    double dz0, dz1, dh0, dh1;
    {
      const unsigned long long* pzp = (const unsigned long long*)(ACCp + 2 * tid);
      const unsigned long long* php = (const unsigned long long*)(ACCp + 512 + 2 * tid);
      for (;;) {
        unsigned long long a0 = __hip_atomic_load(pzp,     __ATOMIC_RELAXED, __HIP_MEMORY_SCOPE_AGENT);
        unsigned long long a1 = __hip_atomic_load(pzp + 1, __ATOMIC_RELAXED, __HIP_MEMORY_SCOPE_AGENT);
        unsigned long long a2 = __hip_atomic_load(php,     __ATOMIC_RELAXED, __HIP_MEMORY_SCOPE_AGENT);
        unsigned long long a3 = __hip_atomic_load(php + 1, __ATOMIC_RELAXED, __HIP_MEMORY_SCOPE_AGENT);
        dz0 = __builtin_bit_cast(double, a0);
        dz1 = __builtin_bit_cast(double, a1);
        dh0 = __builtin_bit_cast(double, a2);
        dh1 = __builtin_bit_cast(double, a3);
        double m = fmin(fmin(dz0, dz1), fmin(dh0, dh1));
        if (m >= ACC_THRESH) break;
        if (--spin_budget <= 0) { dz0 = dz1 = dh0 = dh1 = ACC_FULL; break; }  // fail-safe
      }
    }

    // ---- zero phase (t+2)%3 (gated on this WG's poll; see proof above) ----
    {
      int q = (t + 2) % 3;
      if (tid < 64)
        __hip_atomic_store((unsigned long long*)(ACCb + q * 1024 + slice * 64 + tid),
                           0ULL, __ATOMIC_RELAXED, __HIP_MEMORY_SCOPE_AGENT);
    }

    // ---- assemble h(t+1) rows 2tid, 2tid+1 (identical math in every WG) ----
    {
      float fz0 = (float)((dz0 - ACC_FULL) * ACC_INVSCALE);
      float fz1 = (float)((dz1 - ACC_FULL) * ACC_INVSCALE);
      float fh0 = (float)((dh0 - ACC_FULL) * ACC_INVSCALE);
      float fh1 = (float)((dh1 - ACC_FULL) * ACC_INVSCALE);
      float z0 = 1.f / (1.f + expf(-(bflo(gzu) + fz0)));
      float z1 = 1.f / (1.f + expf(-(bfhi(gzu) + fz1)));
      float hp0 = tanhf(bflo(ghu) + fh0);
      float hp1 = tanhf(bfhi(ghu) + fh1);
      float h0 = hbuf[2 * tid], h1 = hbuf[2 * tid + 1];
      hbuf[2 * tid] = (1.f - z0) * h0 + z0 * hp0;
      hbuf[2 * tid + 1] = (1.f - z1) * h1 + z1 * hp1;
    }
    gzu = gzu2; ghu = ghu2;
    if (tid < 16) { grbuf[2 * tid] = bflo(gru2); grbuf[2 * tid + 1] = bfhi(gru2); }

    // barrier 2 (raw): LDS-only drain — zero-store ACK intentionally left in
    // flight; it is enforced at next iteration's barrier-1 vmcnt drain.
    asm volatile("s_waitcnt lgkmcnt(0)" ::: "memory");
    __builtin_amdgcn_s_barrier();
    asm volatile("" ::: "memory");
  }

  // every WG holds the full final h; slice 0 writes it out
  if (slice == 0) {
    Hout[(size_t)b * DH + 2 * tid] = hbuf[2 * tid];
    Hout[(size_t)b * DH + 2 * tid + 1] = hbuf[2 * tid + 1];
  }
}

// ---------------------------------------------------------------------------
// classifier: out[8][10] = h_final @ W_c^T
// ---------------------------------------------------------------------------
__global__ void classifier_kernel(const float* __restrict__ Hout,
                                  const float* __restrict__ Wc,
                                  float* __restrict__ out) {
  int tid = threadIdx.x;
  if (tid < 80) {
    int b = tid / 10, c = tid % 10;
    const float* h = Hout + (size_t)b * DH;
    const float* w = Wc + (size_t)c * DH;
    float s = 0.f;
    for (int i = 0; i < DH; ++i) s += h[i] * w[i];
    out[tid] = s;
  }
}

extern "C" void kernel_launch(void* const* d_in, const int* in_sizes, int n_in,
                              void* d_out, int out_size, void* d_ws, size_t ws_size,
                              hipStream_t stream) {
  const float* X = (const float*)d_in[0];
  const float* Wlm = (const float*)d_in[1];
  const float* Wz = (const float*)d_in[2];
  const float* Wr = (const float*)d_in[3];
  const float* Wh = (const float*)d_in[4];
  const float* Wc = (const float*)d_in[5];
  float* out = (float*)d_out;

  char* ws = (char*)d_ws;
  unsigned short* seqb = (unsigned short*)ws;              // 33,554,432 B
  unsigned short* G = (unsigned short*)(ws + 33554432);    // 100,663,296 B
  unsigned short* Wp = (unsigned short*)(ws + 134217728);  // 1,572,864 B
  double* ACCd = (double*)(ws + 135790592);                // 196,608 B
  float* Hout = (float*)(ws + 135987200);                  // 16,384 B

  init_state<<<96, 256, 0, stream>>>((unsigned long long*)ACCd);
  pack_w<<<768, 1024, 0, stream>>>(Wz, Wr, Wh, Wp);
  gemm1_kernel<<<dim3(512, 8), 256, 0, stream>>>(X, Wlm, seqb);
  gemm2_kernel<<<dim3(512, 24), 256, 0, stream>>>(seqb, Wp, G);

  {
    const int scan_lds = 100608;
    hipFuncSetAttribute((const void*)scan_kernel,
                        hipFuncAttributeMaxDynamicSharedMemorySize, scan_lds);
    const unsigned short* Gc = G;
    double* ACCp = ACCd;
    float* Hp = Hout;
    void* args[] = {(void*)&Gc, (void*)&Wz, (void*)&Wr, (void*)&Wh,
                    (void*)&ACCp, (void*)&Hp};
    hipLaunchCooperativeKernel((const void*)scan_kernel, dim3(NWG), dim3(256),
                               args, scan_lds, stream);
  }
  classifier_kernel<<<1, 128, 0, stream>>>(Hout, Wc, out);
}